// Round 1
// baseline (2240.227 us; speedup 1.0000x reference)
//
#include <hip/hip_runtime.h>

// Problem constants (from reference)
#define NN 50000
#define NE 800000
#define IN_F 128
#define H1_F 64
#define H2_F 32
#define OUT_F 40

static inline int cdiv(int a, int b) { return (a + b - 1) / b; }

// ---------------- degree / dinv ----------------
__global__ void deg_init_k(float* __restrict__ deg) {
    int i = blockIdx.x * 256 + threadIdx.x;
    if (i < NN) deg[i] = 1.0f;   // self-loop contributes 1 to every node's degree
}

__global__ void deg_count_k(const int* __restrict__ dst, float* __restrict__ deg) {
    int e = blockIdx.x * 256 + threadIdx.x;
    if (e < NE) atomicAdd(&deg[dst[e]], 1.0f);
}

__global__ void dinv_k(float* __restrict__ deg) {
    int i = blockIdx.x * 256 + threadIdx.x;
    if (i < NN) deg[i] = rsqrtf(deg[i]);   // deg >= 1 always (self-loop)
}

// ---------------- small GEMM: Y[N,F] = X[N,K] @ W[K,F] (+bias) (+relu) ----------------
template<int K, int F, bool BIAS, bool RELU>
__global__ void gemm_k(const float* __restrict__ X, const float* __restrict__ W,
                       const float* __restrict__ b, float* __restrict__ Y) {
    __shared__ float Ws[K * F];
    for (int i = threadIdx.x; i < K * F; i += 256) Ws[i] = W[i];
    __syncthreads();
    const int total = NN * F;
    for (int idx = blockIdx.x * 256 + threadIdx.x; idx < total; idx += gridDim.x * 256) {
        int r = idx / F, c = idx - r * F;
        const float* xr = X + (size_t)r * K;
        float acc = BIAS ? b[c] : 0.0f;
        #pragma unroll
        for (int k = 0; k < K; ++k) acc = fmaf(xr[k], Ws[k * F + c], acc);
        if (RELU) acc = fmaxf(acc, 0.0f);
        Y[idx] = acc;
    }
}

// ---------------- propagation: out = A_hat @ h ----------------
// self-loop term also serves as the output initialization (ws is poisoned)
template<int F>
__global__ void prop_self_k(const float* __restrict__ h, const float* __restrict__ dinv,
                            float* __restrict__ out) {
    int idx = blockIdx.x * 256 + threadIdx.x;
    if (idx < NN * F) {
        int node = idx / F;
        float w = dinv[node];
        out[idx] = w * w * h[idx];
    }
}

template<int F>
__global__ void prop_edge_k(const float* __restrict__ h, const int* __restrict__ src,
                            const int* __restrict__ dst, const float* __restrict__ dinv,
                            float* __restrict__ out) {
    constexpr int TPE = F / 4;       // threads per edge (float4 each)
    constexpr int EPB = 256 / TPE;   // edges per block
    int e = blockIdx.x * EPB + threadIdx.x / TPE;
    if (e >= NE) return;
    int l = threadIdx.x % TPE;
    int s = src[e], d = dst[e];
    float w = dinv[s] * dinv[d];
    const float4 v = *reinterpret_cast<const float4*>(h + (size_t)s * F + 4 * l);
    float* o = out + (size_t)d * F + 4 * l;
    atomicAdd(o + 0, w * v.x);
    atomicAdd(o + 1, w * v.y);
    atomicAdd(o + 2, w * v.z);
    atomicAdd(o + 3, w * v.w);
}

// ---------------- bias + relu (optionally writing to a different buffer) ----------------
template<int F>
__global__ void bias_relu_k(const float* __restrict__ h, const float* __restrict__ b,
                            float* __restrict__ out) {
    int idx = blockIdx.x * 256 + threadIdx.x;
    if (idx < NN * F) {
        int c = idx % F;
        out[idx] = fmaxf(h[idx] + b[c], 0.0f);
    }
}

extern "C" void kernel_launch(void* const* d_in, const int* in_sizes, int n_in,
                              void* d_out, int out_size, void* d_ws, size_t ws_size,
                              hipStream_t stream) {
    const float* x  = (const float*)d_in[0];
    const int*   ei = (const int*)d_in[1];
    const float* W1 = (const float*)d_in[2];
    const float* b1 = (const float*)d_in[3];
    const float* W2 = (const float*)d_in[4];
    const float* b2 = (const float*)d_in[5];
    const float* Wf = (const float*)d_in[6];
    const float* bf = (const float*)d_in[7];

    float* out    = (float*)d_out;
    float* embOut = out;                       // [N, 32]
    float* logits = out + (size_t)NN * H2_F;   // [N, 40]

    const int* src = ei;        // edge_index[0]
    const int* dst = ei + NE;   // edge_index[1]

    float* ws   = (float*)d_ws;
    float* dinv = ws;                        // N floats
    float* bufA = ws + NN;                   // N*64 floats (16B-aligned: 200000 % 16 == 0)
    float* bufB = bufA + (size_t)NN * 64;    // N*64 floats

    // ---- degrees -> dinv ----
    deg_init_k<<<cdiv(NN, 256), 256, 0, stream>>>(dinv);
    deg_count_k<<<cdiv(NE, 256), 256, 0, stream>>>(dst, dinv);
    dinv_k<<<cdiv(NN, 256), 256, 0, stream>>>(dinv);

    // ---- layer 1: h = relu(A^2 (x @ W1) + b1) ----
    gemm_k<IN_F, H1_F, false, false>
        <<<cdiv(NN * H1_F, 256), 256, 0, stream>>>(x, W1, nullptr, bufA);

    prop_self_k<H1_F><<<cdiv(NN * H1_F, 256), 256, 0, stream>>>(bufA, dinv, bufB);
    prop_edge_k<H1_F><<<cdiv(NE, 256 / (H1_F / 4)), 256, 0, stream>>>(bufA, src, dst, dinv, bufB);

    prop_self_k<H1_F><<<cdiv(NN * H1_F, 256), 256, 0, stream>>>(bufB, dinv, bufA);
    prop_edge_k<H1_F><<<cdiv(NE, 256 / (H1_F / 4)), 256, 0, stream>>>(bufB, src, dst, dinv, bufA);

    bias_relu_k<H1_F><<<cdiv(NN * H1_F, 256), 256, 0, stream>>>(bufA, b1, bufA);

    // ---- layer 2: emb = relu(A^2 (h @ W2) + b2) ----
    gemm_k<H1_F, H2_F, false, false>
        <<<cdiv(NN * H2_F, 256), 256, 0, stream>>>(bufA, W2, nullptr, bufB);

    prop_self_k<H2_F><<<cdiv(NN * H2_F, 256), 256, 0, stream>>>(bufB, dinv, bufA);
    prop_edge_k<H2_F><<<cdiv(NE, 256 / (H2_F / 4)), 256, 0, stream>>>(bufB, src, dst, dinv, bufA);

    prop_self_k<H2_F><<<cdiv(NN * H2_F, 256), 256, 0, stream>>>(bufA, dinv, bufB);
    prop_edge_k<H2_F><<<cdiv(NE, 256 / (H2_F / 4)), 256, 0, stream>>>(bufA, src, dst, dinv, bufB);

    bias_relu_k<H2_F><<<cdiv(NN * H2_F, 256), 256, 0, stream>>>(bufB, b2, embOut);

    // ---- final linear: logits = emb @ Wf + bf ----
    gemm_k<H2_F, OUT_F, true, false>
        <<<cdiv(NN * OUT_F, 256), 256, 0, stream>>>(embOut, Wf, bf, logits);
}

// Round 2
// 491.962 us; speedup vs baseline: 4.5537x; 4.5537x over previous
//
#include <hip/hip_runtime.h>

// Problem constants (from reference)
#define NN 50000
#define NE 800000
#define IN_F 128
#define H1_F 64
#define H2_F 32
#define OUT_F 40

static inline int cdiv(int a, int b) { return (a + b - 1) / b; }

// ---------------- CSR build ----------------
__global__ void cnt_init_k(int* __restrict__ cnt) {
    int i = blockIdx.x * 256 + threadIdx.x;
    if (i < NN) cnt[i] = 0;
}

__global__ void cnt_count_k(const int* __restrict__ dst, int* __restrict__ cnt) {
    int e = blockIdx.x * 256 + threadIdx.x;
    if (e < NE) atomicAdd(&cnt[dst[e]], 1);
}

__global__ void dinv_k(const int* __restrict__ cnt, float* __restrict__ dinv) {
    int i = blockIdx.x * 256 + threadIdx.x;
    if (i < NN) dinv[i] = rsqrtf((float)cnt[i] + 1.0f);  // +1 self-loop
}

// single-block exclusive prefix scan: cursor[i] = sum(cnt[0..i-1])
__global__ void scan_k(const int* __restrict__ cnt, int* __restrict__ cursor) {
    __shared__ int sh[1024];
    __shared__ int carry;
    const int tid = threadIdx.x;
    if (tid == 0) carry = 0;
    __syncthreads();
    for (int base = 0; base < NN; base += 1024) {
        int i = base + tid;
        int v = (i < NN) ? cnt[i] : 0;
        sh[tid] = v;
        __syncthreads();
        for (int off = 1; off < 1024; off <<= 1) {
            int t = (tid >= off) ? sh[tid - off] : 0;
            __syncthreads();
            sh[tid] += t;
            __syncthreads();
        }
        if (i < NN) cursor[i] = carry + sh[tid] - v;   // exclusive
        __syncthreads();                                // all reads of carry/sh done
        if (tid == 0) carry += sh[1023];
        __syncthreads();                                // carry visible, sh reusable
    }
}

// scatter edges by dst; afterwards cursor[d] == row end of d (beg = cursor[d-1])
__global__ void scatter_k(const int* __restrict__ src, const int* __restrict__ dst,
                          int* __restrict__ cursor, int* __restrict__ csr) {
    int e = blockIdx.x * 256 + threadIdx.x;
    if (e < NE) {
        int pos = atomicAdd(&cursor[dst[e]], 1);
        csr[pos] = src[e];
    }
}

// ---------------- small GEMM: Y[N,F] = X[N,K] @ W[K,F] (+bias) (+row scale) ----------------
template<int K, int F, bool BIAS, bool SCALE>
__global__ void gemm_k(const float* __restrict__ X, const float* __restrict__ W,
                       const float* __restrict__ b, const float* __restrict__ dinv,
                       float* __restrict__ Y) {
    __shared__ float Ws[K * F];
    for (int i = threadIdx.x; i < K * F; i += 256) Ws[i] = W[i];
    __syncthreads();
    const int total = NN * F;
    for (int idx = blockIdx.x * 256 + threadIdx.x; idx < total; idx += gridDim.x * 256) {
        int r = idx / F, c = idx - r * F;
        const float* xr = X + (size_t)r * K;
        float acc = BIAS ? b[c] : 0.0f;
        #pragma unroll
        for (int k = 0; k < K; ++k) acc = fmaf(xr[k], Ws[k * F + c], acc);
        if (SCALE) acc *= dinv[r];
        Y[idx] = acc;
    }
}

// ---------------- pull propagation: out[d] = sc(d) * (in[d] + sum_{s in N(d)} in[s]) ----------------
// SQ: sc = dinv^2 (intermediate hop);  else sc = dinv (final hop)
// EPI: out = relu(sc*sum + bias)
template<int F, bool SQ, bool EPI>
__global__ void pull_k(const float* __restrict__ in, const int* __restrict__ csr,
                       const int* __restrict__ cursor, const float* __restrict__ dinv,
                       const float* __restrict__ b, float* __restrict__ out) {
    constexpr int NPB = 256 / F;                    // nodes per block
    int node = blockIdx.x * NPB + threadIdx.x / F;
    int lane = threadIdx.x % F;
    if (node >= NN) return;
    int beg = (node == 0) ? 0 : cursor[node - 1];
    int end = cursor[node];
    const size_t off = (size_t)node * F + lane;
    float acc = in[off];                            // self-loop (weight 1 in pure-sum space)
    int k = beg;
    for (; k + 3 < end; k += 4) {
        int s0 = csr[k], s1 = csr[k + 1], s2 = csr[k + 2], s3 = csr[k + 3];
        float a0 = in[(size_t)s0 * F + lane];
        float a1 = in[(size_t)s1 * F + lane];
        float a2 = in[(size_t)s2 * F + lane];
        float a3 = in[(size_t)s3 * F + lane];
        acc += a0 + a1 + a2 + a3;
    }
    for (; k < end; ++k) acc += in[(size_t)csr[k] * F + lane];
    float sc = dinv[node];
    if (SQ) sc *= sc;
    float r = sc * acc;
    if (EPI) r = fmaxf(r + b[lane], 0.0f);
    out[off] = r;
}

extern "C" void kernel_launch(void* const* d_in, const int* in_sizes, int n_in,
                              void* d_out, int out_size, void* d_ws, size_t ws_size,
                              hipStream_t stream) {
    const float* x  = (const float*)d_in[0];
    const int*   ei = (const int*)d_in[1];
    const float* W1 = (const float*)d_in[2];
    const float* b1 = (const float*)d_in[3];
    const float* W2 = (const float*)d_in[4];
    const float* b2 = (const float*)d_in[5];
    const float* Wf = (const float*)d_in[6];
    const float* bf = (const float*)d_in[7];

    float* out    = (float*)d_out;
    float* embOut = out;                       // [N, 32]
    float* logits = out + (size_t)NN * H2_F;   // [N, 40]

    const int* src = ei;        // edge_index[0]
    const int* dst = ei + NE;   // edge_index[1]

    // workspace layout
    float* ws     = (float*)d_ws;
    float* dinv   = ws;                          // N f32
    int*   cnt    = (int*)(ws + NN);             // N i32
    int*   cursor = cnt + NN;                    // N i32
    int*   csr    = cursor + NN;                 // E i32
    float* bufA   = (float*)(csr + NE);          // N*64 f32
    float* bufB   = bufA + (size_t)NN * 64;      // N*64 f32

    // ---- CSR build + dinv ----
    cnt_init_k<<<cdiv(NN, 256), 256, 0, stream>>>(cnt);
    cnt_count_k<<<cdiv(NE, 256), 256, 0, stream>>>(dst, cnt);
    dinv_k<<<cdiv(NN, 256), 256, 0, stream>>>(cnt, dinv);
    scan_k<<<1, 1024, 0, stream>>>(cnt, cursor);
    scatter_k<<<cdiv(NE, 256), 256, 0, stream>>>(src, dst, cursor, csr);

    // ---- layer 1: h = relu(A^2 (x @ W1) + b1), normalization folded into epilogues ----
    gemm_k<IN_F, H1_F, false, true>
        <<<cdiv(NN * H1_F, 256), 256, 0, stream>>>(x, W1, nullptr, dinv, bufA);   // t = dinv*(xW1)
    pull_k<H1_F, true, false>
        <<<cdiv(NN, 256 / H1_F), 256, 0, stream>>>(bufA, csr, cursor, dinv, nullptr, bufB);  // v = dinv^2 * sum
    pull_k<H1_F, false, true>
        <<<cdiv(NN, 256 / H1_F), 256, 0, stream>>>(bufB, csr, cursor, dinv, b1, bufA);       // h = relu(dinv*sum + b1)

    // ---- layer 2: emb = relu(A^2 (h @ W2) + b2) ----
    gemm_k<H1_F, H2_F, false, true>
        <<<cdiv(NN * H2_F, 256), 256, 0, stream>>>(bufA, W2, nullptr, dinv, bufB);
    pull_k<H2_F, true, false>
        <<<cdiv(NN, 256 / H2_F), 256, 0, stream>>>(bufB, csr, cursor, dinv, nullptr, bufA);
    pull_k<H2_F, false, true>
        <<<cdiv(NN, 256 / H2_F), 256, 0, stream>>>(bufA, csr, cursor, dinv, b2, embOut);

    // ---- final linear: logits = emb @ Wf + bf ----
    gemm_k<H2_F, OUT_F, true, false>
        <<<cdiv(NN * OUT_F, 256), 256, 0, stream>>>(embOut, Wf, bf, nullptr, logits);
}

// Round 4
// 347.043 us; speedup vs baseline: 6.4552x; 1.4176x over previous
//
#include <hip/hip_runtime.h>

// Problem constants (from reference)
#define NN 50000
#define NE 800000
#define IN_F 128
#define H1_F 64
#define H2_F 32
#define OUT_F 40

#define SCAN_CHUNK 1024
#define SCAN_NB ((NN + SCAN_CHUNK - 1) / SCAN_CHUNK)   // 49

static inline int cdiv(int a, int b) { return (a + b - 1) / b; }

// ---------------- CSR build ----------------
__global__ void cnt_init_k(int* __restrict__ cnt) {
    int i = blockIdx.x * 256 + threadIdx.x;
    if (i < NN) cnt[i] = 0;
}

__global__ void cnt_count_k(const int* __restrict__ dst, int* __restrict__ cnt) {
    int e = blockIdx.x * 256 + threadIdx.x;
    if (e < NE) atomicAdd(&cnt[dst[e]], 1);
}

__global__ void dinv_k(const int* __restrict__ cnt, float* __restrict__ dinv) {
    int i = blockIdx.x * 256 + threadIdx.x;
    if (i < NN) dinv[i] = rsqrtf((float)cnt[i] + 1.0f);  // +1 self-loop
}

// hierarchical exclusive scan: cursor[i] = sum(cnt[0..i-1])
__global__ void scan1_k(const int* __restrict__ cnt, int* __restrict__ cursor,
                        int* __restrict__ partials) {
    __shared__ int sh[256];
    const int tid = threadIdx.x;
    const int base = blockIdx.x * SCAN_CHUNK + tid * 4;
    int c0 = 0, c1 = 0, c2 = 0, c3 = 0;
    if (base + 3 < NN) {
        int4 v = *reinterpret_cast<const int4*>(cnt + base);
        c0 = v.x; c1 = v.y; c2 = v.z; c3 = v.w;
    } else {
        if (base + 0 < NN) c0 = cnt[base + 0];
        if (base + 1 < NN) c1 = cnt[base + 1];
        if (base + 2 < NN) c2 = cnt[base + 2];
    }
    int s = c0 + c1 + c2 + c3;
    sh[tid] = s;
    __syncthreads();
    for (int off = 1; off < 256; off <<= 1) {
        int t = (tid >= off) ? sh[tid - off] : 0;
        __syncthreads();
        sh[tid] += t;
        __syncthreads();
    }
    int ex = sh[tid] - s;   // exclusive within block
    if (tid == 255) partials[blockIdx.x] = sh[255];
    if (base + 0 < NN) cursor[base + 0] = ex;
    if (base + 1 < NN) cursor[base + 1] = ex + c0;
    if (base + 2 < NN) cursor[base + 2] = ex + c0 + c1;
    if (base + 3 < NN) cursor[base + 3] = ex + c0 + c1 + c2;
}

__global__ void scan2_k(int* __restrict__ partials) {   // exclusive scan of SCAN_NB elems, in place
    __shared__ int sh[64];
    int tid = threadIdx.x;
    int v = (tid < SCAN_NB) ? partials[tid] : 0;
    sh[tid] = v;
    __syncthreads();
    for (int off = 1; off < 64; off <<= 1) {
        int t = (tid >= off) ? sh[tid - off] : 0;
        __syncthreads();
        sh[tid] += t;
        __syncthreads();
    }
    if (tid < SCAN_NB) partials[tid] = sh[tid] - v;
}

__global__ void scan3_k(int* __restrict__ cursor, const int* __restrict__ partials) {
    int i = blockIdx.x * 256 + threadIdx.x;
    if (i < NN) cursor[i] += partials[i / SCAN_CHUNK];
}

// scatter edges by dst; afterwards cursor[d] == row end of d (beg = cursor[d-1])
__global__ void scatter_k(const int* __restrict__ src, const int* __restrict__ dst,
                          int* __restrict__ cursor, int* __restrict__ csr) {
    int e = blockIdx.x * 256 + threadIdx.x;
    if (e < NE) {
        int pos = atomicAdd(&cursor[dst[e]], 1);
        csr[pos] = src[e];
    }
}

// ---------------- register-tiled GEMM: Y[N,F] = X[N,K] @ W[K,F] (+bias) (+row scale) ----
// Tile: TR=RT*RPT rows x F cols per block. Thread (tr,tc): RPT rows x 4 cols.
// KT=32 k-tile staged in LDS (Xs padded to kill bank conflicts).
template<int K, int F, int CT, int RPT, int BLOCK, bool BIAS, bool SCALE>
__global__ __launch_bounds__(BLOCK)
void gemm_tile_k(const float* __restrict__ X, const float* __restrict__ W,
                 const float* __restrict__ b, const float* __restrict__ dinv,
                 float* __restrict__ Y) {
    constexpr int RT = BLOCK / CT;
    constexpr int TR = RT * RPT;            // tile rows (64 for all instantiations)
    constexpr int KT = 32;
    constexpr int KPAD = KT + 1;
    __shared__ float Xs[TR][KPAD];
    __shared__ float Wsh[KT][F];
    const int rowBase = blockIdx.x * TR;
    const int tc = threadIdx.x % CT;
    const int tr = threadIdx.x / CT;

    float acc[RPT][4];
    #pragma unroll
    for (int i = 0; i < RPT; ++i)
        #pragma unroll
        for (int j = 0; j < 4; ++j) acc[i][j] = 0.0f;

    for (int k0 = 0; k0 < K; k0 += KT) {
        constexpr int XL4 = TR * KT / 4;
        for (int l = threadIdx.x; l < XL4; l += BLOCK) {
            int r  = l / (KT / 4);
            int kk = (l % (KT / 4)) * 4;
            float4 v = make_float4(0.f, 0.f, 0.f, 0.f);
            int gr = rowBase + r;
            if (gr < NN) v = *reinterpret_cast<const float4*>(X + (size_t)gr * K + k0 + kk);
            Xs[r][kk + 0] = v.x; Xs[r][kk + 1] = v.y;
            Xs[r][kk + 2] = v.z; Xs[r][kk + 3] = v.w;
        }
        constexpr int WL4 = KT * F / 4;
        for (int l = threadIdx.x; l < WL4; l += BLOCK) {
            int kk = l / (F / 4);
            int c  = (l % (F / 4)) * 4;
            *reinterpret_cast<float4*>(&Wsh[kk][c]) =
                *reinterpret_cast<const float4*>(W + (size_t)(k0 + kk) * F + c);
        }
        __syncthreads();
        #pragma unroll
        for (int kk = 0; kk < KT; ++kk) {
            float wv[4];
            *reinterpret_cast<float4*>(wv) = *reinterpret_cast<const float4*>(&Wsh[kk][tc * 4]);
            #pragma unroll
            for (int i = 0; i < RPT; ++i) {
                float a = Xs[tr * RPT + i][kk];
                acc[i][0] = fmaf(a, wv[0], acc[i][0]);
                acc[i][1] = fmaf(a, wv[1], acc[i][1]);
                acc[i][2] = fmaf(a, wv[2], acc[i][2]);
                acc[i][3] = fmaf(a, wv[3], acc[i][3]);
            }
        }
        __syncthreads();
    }
    #pragma unroll
    for (int i = 0; i < RPT; ++i) {
        int gr = rowBase + tr * RPT + i;
        if (gr < NN) {
            float sc = SCALE ? dinv[gr] : 1.0f;
            float4 v;
            v.x = acc[i][0]; v.y = acc[i][1]; v.z = acc[i][2]; v.w = acc[i][3];
            if (BIAS) {
                v.x += b[tc * 4 + 0]; v.y += b[tc * 4 + 1];
                v.z += b[tc * 4 + 2]; v.w += b[tc * 4 + 3];
            }
            v.x *= sc; v.y *= sc; v.z *= sc; v.w *= sc;
            *reinterpret_cast<float4*>(Y + (size_t)gr * F + tc * 4) = v;
        }
    }
}

// ---------------- pull propagation: out[d] = sc(d) * (in[d] + sum_{s in N(d)} in[s]) ----
// SQ: sc = dinv^2 (intermediate hop);  else sc = dinv (final hop)
// EPI: out = relu(sc*sum + bias)
template<int F, bool SQ, bool EPI>
__global__ void pull_k(const float* __restrict__ in, const int* __restrict__ csr,
                       const int* __restrict__ cursor, const float* __restrict__ dinv,
                       const float* __restrict__ b, float* __restrict__ out) {
    constexpr int NPB = 256 / F;                    // nodes per block
    int node = blockIdx.x * NPB + threadIdx.x / F;
    int lane = threadIdx.x % F;
    if (node >= NN) return;
    int beg = (node == 0) ? 0 : cursor[node - 1];
    int end = cursor[node];
    const size_t off = (size_t)node * F + lane;
    float acc = in[off];                            // self-loop
    int k = beg;
    for (; k + 3 < end; k += 4) {
        int s0 = csr[k], s1 = csr[k + 1], s2 = csr[k + 2], s3 = csr[k + 3];
        float a0 = in[(size_t)s0 * F + lane];
        float a1 = in[(size_t)s1 * F + lane];
        float a2 = in[(size_t)s2 * F + lane];
        float a3 = in[(size_t)s3 * F + lane];
        acc += a0 + a1 + a2 + a3;
    }
    for (; k < end; ++k) acc += in[(size_t)csr[k] * F + lane];
    float sc = dinv[node];
    if (SQ) sc *= sc;
    float r = sc * acc;
    if (EPI) r = fmaxf(r + b[lane], 0.0f);
    out[off] = r;
}

extern "C" void kernel_launch(void* const* d_in, const int* in_sizes, int n_in,
                              void* d_out, int out_size, void* d_ws, size_t ws_size,
                              hipStream_t stream) {
    const float* x  = (const float*)d_in[0];
    const int*   ei = (const int*)d_in[1];
    const float* W1 = (const float*)d_in[2];
    const float* b1 = (const float*)d_in[3];
    const float* W2 = (const float*)d_in[4];
    const float* b2 = (const float*)d_in[5];
    const float* Wf = (const float*)d_in[6];
    const float* bf = (const float*)d_in[7];

    float* out    = (float*)d_out;
    float* embOut = out;                       // [N, 32]
    float* logits = out + (size_t)NN * H2_F;   // [N, 40]

    const int* src = ei;        // edge_index[0]
    const int* dst = ei + NE;   // edge_index[1]

    // workspace layout
    float* ws       = (float*)d_ws;
    float* dinv     = ws;                          // N f32
    int*   cnt      = (int*)(ws + NN);             // N i32 (16B aligned: 200000%16==0)
    int*   cursor   = cnt + NN;                    // N i32
    int*   csr      = cursor + NN;                 // E i32
    int*   partials = csr + NE;                    // 64 i32
    float* bufA     = (float*)(partials + 64);     // N*64 f32
    float* bufB     = bufA + (size_t)NN * 64;      // N*64 f32

    // ---- CSR build + dinv ----
    cnt_init_k<<<cdiv(NN, 256), 256, 0, stream>>>(cnt);
    cnt_count_k<<<cdiv(NE, 256), 256, 0, stream>>>(dst, cnt);
    dinv_k<<<cdiv(NN, 256), 256, 0, stream>>>(cnt, dinv);
    scan1_k<<<SCAN_NB, 256, 0, stream>>>(cnt, cursor, partials);
    scan2_k<<<1, 64, 0, stream>>>(partials);
    scan3_k<<<cdiv(NN, 256), 256, 0, stream>>>(cursor, partials);
    scatter_k<<<cdiv(NE, 256), 256, 0, stream>>>(src, dst, cursor, csr);

    // ---- layer 1: h = relu(A^2 (x @ W1) + b1), normalization folded into epilogues ----
    gemm_tile_k<IN_F, H1_F, 16, 4, 256, false, true>
        <<<cdiv(NN, 64), 256, 0, stream>>>(x, W1, nullptr, dinv, bufA);          // t = dinv*(xW1)
    pull_k<H1_F, true, false>
        <<<cdiv(NN, 256 / H1_F), 256, 0, stream>>>(bufA, csr, cursor, dinv, nullptr, bufB);
    pull_k<H1_F, false, true>
        <<<cdiv(NN, 256 / H1_F), 256, 0, stream>>>(bufB, csr, cursor, dinv, b1, bufA);

    // ---- layer 2: emb = relu(A^2 (h @ W2) + b2) ----
    gemm_tile_k<H1_F, H2_F, 8, 2, 256, false, true>
        <<<cdiv(NN, 64), 256, 0, stream>>>(bufA, W2, nullptr, dinv, bufB);
    pull_k<H2_F, true, false>
        <<<cdiv(NN, 256 / H2_F), 256, 0, stream>>>(bufB, csr, cursor, dinv, nullptr, bufA);
    pull_k<H2_F, false, true>
        <<<cdiv(NN, 256 / H2_F), 256, 0, stream>>>(bufA, csr, cursor, dinv, b2, embOut);

    // ---- final linear: logits = emb @ Wf + bf ----
    gemm_tile_k<H2_F, OUT_F, 10, 2, 320, true, false>
        <<<cdiv(NN, 64), 320, 0, stream>>>(embOut, Wf, bf, nullptr, logits);
}

// Round 6
// 245.123 us; speedup vs baseline: 9.1392x; 1.4158x over previous
//
#include <hip/hip_runtime.h>

// Problem constants (from reference)
#define NN 50000
#define NE 800000
#define IN_F 128
#define H1_F 64
#define H2_F 32
#define OUT_F 40

// bucketized CSR build
#define BSH 7                    // bucket = dst >> 7  (128 nodes per bucket)
#define NBKT 391                 // ceil(50000 / 128)
#define CAPA 4032                // per-bucket capacity (avg 2046, max ~2300; 12.6MB total, aliases bufB)
#define CHUNK 4096               // edges per binA block
#define NCH ((NE + CHUNK - 1) / CHUNK)   // 196

static inline int cdiv(int a, int b) { return (a + b - 1) / b; }

// ---------------- CSR build v2: two-phase bucketized counting sort ----------------
__global__ void initcur_k(int* __restrict__ gCursor) {
    int b = blockIdx.x * 256 + threadIdx.x;
    if (b < NBKT) gCursor[b] = b * CAPA;
}

// Phase A: bin a 4096-edge chunk by dst>>7 in LDS, append runs to global bucket regions.
__global__ __launch_bounds__(256)
void binA_k(const int* __restrict__ src, const int* __restrict__ dst,
            uint2* __restrict__ pairs, int* __restrict__ gCursor) {
    __shared__ int hist[512], incl[512], runSt[512], lcur[512], baseSh[512];
    __shared__ uint2 stage[CHUNK];
    const int t = threadIdx.x;
    const int e0 = blockIdx.x * CHUNK;
    const int n = min(CHUNK, NE - e0);

    hist[t] = 0; hist[t + 256] = 0;
    __syncthreads();
    for (int i = t; i < n; i += 256) {
        int d = dst[e0 + i];
        atomicAdd(&hist[d >> BSH], 1);
    }
    __syncthreads();
    incl[t] = hist[t]; incl[t + 256] = hist[t + 256];
    __syncthreads();
    // inclusive Hillis-Steele scan over 512 slots with 256 threads
    for (int off = 1; off < 512; off <<= 1) {
        int v0 = (t >= off) ? incl[t - off] : 0;
        int v1 = (t + 256 >= off) ? incl[t + 256 - off] : 0;
        __syncthreads();
        incl[t] += v0; incl[t + 256] += v1;
        __syncthreads();
    }
    runSt[t] = incl[t] - hist[t];   runSt[t + 256] = incl[t + 256] - hist[t + 256];
    lcur[t]  = runSt[t];            lcur[t + 256]  = runSt[t + 256];
    __syncthreads();
    // LDS scatter (sorted-by-bucket staging)
    for (int i = t; i < n; i += 256) {
        int s = src[e0 + i], d = dst[e0 + i];
        int b = d >> BSH;
        int p = atomicAdd(&lcur[b], 1);
        stage[p] = make_uint2((unsigned)s, (unsigned)d);
    }
    // reserve global space per bucket
    for (int b = t; b < NBKT; b += 256) {
        int c = hist[b];
        baseSh[b] = c ? atomicAdd(&gCursor[b], c) : 0;
    }
    __syncthreads();
    // sequential append per run (coalesced within runs)
    for (int i = t; i < n; i += 256) {
        uint2 p = stage[i];
        int b = (int)(p.y >> BSH);
        int gp = baseSh[b] + (i - runSt[b]);
        if (gp < (b + 1) * CAPA) pairs[gp] = p;   // overflow guard (statistically impossible)
    }
}

// scan of per-bucket counts -> segment bases (single block)
__global__ __launch_bounds__(512)
void segscan_k(const int* __restrict__ gCursor, int* __restrict__ segBase) {
    __shared__ int sh[512], orig[512];
    int t = threadIdx.x;
    int c = 0;
    if (t < NBKT) {
        c = gCursor[t] - t * CAPA;
        c = max(0, min(c, CAPA));
    }
    sh[t] = c; orig[t] = c;
    __syncthreads();
    for (int off = 1; off < 512; off <<= 1) {
        int v = (t >= off) ? sh[t - off] : 0;
        __syncthreads();
        sh[t] += v;
        __syncthreads();
    }
    if (t < NBKT) segBase[t] = sh[t] - orig[t];
}

// Phase B: one block per bucket — histogram (fuses cnt+dinv), local scan (row cursors),
// scatter csr within the block-exclusive segment (XCD-local lines -> no write amplification).
__global__ __launch_bounds__(256)
void binB_k(const uint2* __restrict__ pairs, const int* __restrict__ gCursor,
            const int* __restrict__ segBase, int* __restrict__ cursor,
            float* __restrict__ dinv, int* __restrict__ csr) {
    const int b = blockIdx.x;
    const int nodeBase = b << BSH;
    const int nNodes = min(128, NN - nodeBase);
    int count = gCursor[b] - b * CAPA;
    count = max(0, min(count, CAPA));
    const int seg = segBase[b];
    __shared__ int hist[128], incl[128], lcur[128];
    const int t = threadIdx.x;
    if (t < 128) hist[t] = 0;
    __syncthreads();
    const uint2* bp = pairs + (size_t)b * CAPA;
    for (int i = t; i < count; i += 256) {
        int d = (int)bp[i].y - nodeBase;
        atomicAdd(&hist[d], 1);
    }
    __syncthreads();
    if (t < 128) incl[t] = hist[t];
    __syncthreads();
    for (int off = 1; off < 128; off <<= 1) {
        int v = (t < 128 && t >= off) ? incl[t - off] : 0;
        __syncthreads();
        if (t < 128) incl[t] += v;
        __syncthreads();
    }
    if (t < nNodes) {
        cursor[nodeBase + t] = seg + incl[t];                 // inclusive row end
        dinv[nodeBase + t]   = rsqrtf((float)hist[t] + 1.0f); // +1 self-loop
        lcur[t] = seg + incl[t] - hist[t];                    // row start
    }
    __syncthreads();
    for (int i = t; i < count; i += 256) {
        uint2 p = bp[i];
        int d = (int)p.y - nodeBase;
        int pos = atomicAdd(&lcur[d], 1);
        csr[pos] = (int)p.x;
    }
}

// ---------------- register-tiled GEMM: Y[N,F] = X[N,K] @ W[K,F] (+bias) (+row scale) ----
template<int K, int F, int CT, int RPT, int BLOCK, bool BIAS, bool SCALE>
__global__ __launch_bounds__(BLOCK)
void gemm_tile_k(const float* __restrict__ X, const float* __restrict__ W,
                 const float* __restrict__ b, const float* __restrict__ dinv,
                 float* __restrict__ Y) {
    constexpr int RT = BLOCK / CT;
    constexpr int TR = RT * RPT;
    constexpr int KT = 32;
    constexpr int KPAD = KT + 1;
    __shared__ float Xs[TR][KPAD];
    __shared__ float Wsh[KT][F];
    const int rowBase = blockIdx.x * TR;
    const int tc = threadIdx.x % CT;
    const int tr = threadIdx.x / CT;

    float acc[RPT][4];
    #pragma unroll
    for (int i = 0; i < RPT; ++i)
        #pragma unroll
        for (int j = 0; j < 4; ++j) acc[i][j] = 0.0f;

    for (int k0 = 0; k0 < K; k0 += KT) {
        constexpr int XL4 = TR * KT / 4;
        for (int l = threadIdx.x; l < XL4; l += BLOCK) {
            int r  = l / (KT / 4);
            int kk = (l % (KT / 4)) * 4;
            float4 v = make_float4(0.f, 0.f, 0.f, 0.f);
            int gr = rowBase + r;
            if (gr < NN) v = *reinterpret_cast<const float4*>(X + (size_t)gr * K + k0 + kk);
            Xs[r][kk + 0] = v.x; Xs[r][kk + 1] = v.y;
            Xs[r][kk + 2] = v.z; Xs[r][kk + 3] = v.w;
        }
        constexpr int WL4 = KT * F / 4;
        for (int l = threadIdx.x; l < WL4; l += BLOCK) {
            int kk = l / (F / 4);
            int c  = (l % (F / 4)) * 4;
            *reinterpret_cast<float4*>(&Wsh[kk][c]) =
                *reinterpret_cast<const float4*>(W + (size_t)(k0 + kk) * F + c);
        }
        __syncthreads();
        #pragma unroll
        for (int kk = 0; kk < KT; ++kk) {
            float wv[4];
            *reinterpret_cast<float4*>(wv) = *reinterpret_cast<const float4*>(&Wsh[kk][tc * 4]);
            #pragma unroll
            for (int i = 0; i < RPT; ++i) {
                float a = Xs[tr * RPT + i][kk];
                acc[i][0] = fmaf(a, wv[0], acc[i][0]);
                acc[i][1] = fmaf(a, wv[1], acc[i][1]);
                acc[i][2] = fmaf(a, wv[2], acc[i][2]);
                acc[i][3] = fmaf(a, wv[3], acc[i][3]);
            }
        }
        __syncthreads();
    }
    #pragma unroll
    for (int i = 0; i < RPT; ++i) {
        int gr = rowBase + tr * RPT + i;
        if (gr < NN) {
            float sc = SCALE ? dinv[gr] : 1.0f;
            float4 v;
            v.x = acc[i][0]; v.y = acc[i][1]; v.z = acc[i][2]; v.w = acc[i][3];
            if (BIAS) {
                v.x += b[tc * 4 + 0]; v.y += b[tc * 4 + 1];
                v.z += b[tc * 4 + 2]; v.w += b[tc * 4 + 3];
            }
            v.x *= sc; v.y *= sc; v.z *= sc; v.w *= sc;
            *reinterpret_cast<float4*>(Y + (size_t)gr * F + tc * 4) = v;
        }
    }
}

// ---------------- pull propagation (float4 lanes): out[d] = sc * (in[d] + sum_{s} in[s]) ----
// F/4 lanes per node, each lane owns a float4 column slice -> one dwordx4 gathers 4 rows/wave.
template<int F, bool SQ, bool EPI>
__global__ __launch_bounds__(256)
void pull4_k(const float* __restrict__ in, const int* __restrict__ csr,
             const int* __restrict__ cursor, const float* __restrict__ dinv,
             const float* __restrict__ b, float* __restrict__ out) {
    constexpr int LPN = F / 4;            // lanes per node
    constexpr int NPB = 256 / LPN;        // nodes per block
    const int t = threadIdx.x;
    const int node = blockIdx.x * NPB + t / LPN;
    const int col  = (t % LPN) * 4;
    if (node >= NN) return;
    const int beg = (node == 0) ? 0 : cursor[node - 1];
    const int end = cursor[node];
    const float* base = in + (size_t)node * F + col;
    float4 a0 = *reinterpret_cast<const float4*>(base);   // self-loop
    float4 a1 = make_float4(0.f, 0.f, 0.f, 0.f);
    int k = beg;
    for (; k + 1 < end; k += 2) {
        int s0 = csr[k], s1 = csr[k + 1];
        float4 v0 = *reinterpret_cast<const float4*>(in + (size_t)s0 * F + col);
        float4 v1 = *reinterpret_cast<const float4*>(in + (size_t)s1 * F + col);
        a0.x += v0.x; a0.y += v0.y; a0.z += v0.z; a0.w += v0.w;
        a1.x += v1.x; a1.y += v1.y; a1.z += v1.z; a1.w += v1.w;
    }
    if (k < end) {
        int s0 = csr[k];
        float4 v0 = *reinterpret_cast<const float4*>(in + (size_t)s0 * F + col);
        a0.x += v0.x; a0.y += v0.y; a0.z += v0.z; a0.w += v0.w;
    }
    float sc = dinv[node];
    if (SQ) sc *= sc;
    float4 r;
    r.x = (a0.x + a1.x) * sc; r.y = (a0.y + a1.y) * sc;
    r.z = (a0.z + a1.z) * sc; r.w = (a0.w + a1.w) * sc;
    if (EPI) {
        const float4 bv = *reinterpret_cast<const float4*>(b + col);
        r.x = fmaxf(r.x + bv.x, 0.f); r.y = fmaxf(r.y + bv.y, 0.f);
        r.z = fmaxf(r.z + bv.z, 0.f); r.w = fmaxf(r.w + bv.w, 0.f);
    }
    *reinterpret_cast<float4*>(out + (size_t)node * F + col) = r;
}

extern "C" void kernel_launch(void* const* d_in, const int* in_sizes, int n_in,
                              void* d_out, int out_size, void* d_ws, size_t ws_size,
                              hipStream_t stream) {
    const float* x  = (const float*)d_in[0];
    const int*   ei = (const int*)d_in[1];
    const float* W1 = (const float*)d_in[2];
    const float* b1 = (const float*)d_in[3];
    const float* W2 = (const float*)d_in[4];
    const float* b2 = (const float*)d_in[5];
    const float* Wf = (const float*)d_in[6];
    const float* bf = (const float*)d_in[7];

    float* out    = (float*)d_out;
    float* embOut = out;                       // [N, 32]
    float* logits = out + (size_t)NN * H2_F;   // [N, 40]

    const int* src = ei;        // edge_index[0]
    const int* dst = ei + NE;   // edge_index[1]

    // workspace layout (all offsets 16B-aligned)
    float* ws       = (float*)d_ws;
    float* dinv     = ws;                           // NN f32
    int*   cursor   = (int*)(ws + NN);              // NN i32
    int*   csr      = cursor + NN;                  // NE i32
    int*   gCursor  = csr + NE;                     // 512 i32
    int*   segBase  = gCursor + 512;                // 512 i32
    float* bufA     = (float*)(segBase + 512);      // NN*64 f32
    float* bufB     = bufA + (size_t)NN * 64;       // NN*64 f32
    uint2* pairs    = (uint2*)bufB;                 // NBKT*CAPA uint2 (12.6MB <= bufB, dead before pull#1)

    // ---- CSR build + dinv (bucketized, XCD-local writes) ----
    initcur_k<<<cdiv(NBKT, 256), 256, 0, stream>>>(gCursor);
    binA_k<<<NCH, 256, 0, stream>>>(src, dst, pairs, gCursor);
    segscan_k<<<1, 512, 0, stream>>>(gCursor, segBase);
    binB_k<<<NBKT, 256, 0, stream>>>(pairs, gCursor, segBase, cursor, dinv, csr);

    // ---- layer 1: h = relu(A^2 (x @ W1) + b1), normalization folded into epilogues ----
    gemm_tile_k<IN_F, H1_F, 16, 4, 256, false, true>
        <<<cdiv(NN, 64), 256, 0, stream>>>(x, W1, nullptr, dinv, bufA);   // t = dinv*(xW1)
    pull4_k<H1_F, true, false>
        <<<cdiv(NN, 256 / (H1_F / 4)), 256, 0, stream>>>(bufA, csr, cursor, dinv, nullptr, bufB);
    pull4_k<H1_F, false, true>
        <<<cdiv(NN, 256 / (H1_F / 4)), 256, 0, stream>>>(bufB, csr, cursor, dinv, b1, bufA);

    // ---- layer 2: emb = relu(A^2 (h @ W2) + b2) ----
    gemm_tile_k<H1_F, H2_F, 8, 2, 256, false, true>
        <<<cdiv(NN, 64), 256, 0, stream>>>(bufA, W2, nullptr, dinv, bufB);
    pull4_k<H2_F, true, false>
        <<<cdiv(NN, 256 / (H2_F / 4)), 256, 0, stream>>>(bufB, csr, cursor, dinv, nullptr, bufA);
    pull4_k<H2_F, false, true>
        <<<cdiv(NN, 256 / (H2_F / 4)), 256, 0, stream>>>(bufA, csr, cursor, dinv, b2, embOut);

    // ---- final linear: logits = emb @ Wf + bf ----
    gemm_tile_k<H2_F, OUT_F, 10, 2, 320, true, false>
        <<<cdiv(NN, 64), 320, 0, stream>>>(embOut, Wf, bf, nullptr, logits);
}

// Round 7
// 240.352 us; speedup vs baseline: 9.3206x; 1.0199x over previous
//
#include <hip/hip_runtime.h>

// Problem constants (from reference)
#define NN 50000
#define NE 800000
#define IN_F 128
#define H1_F 64
#define H2_F 32
#define OUT_F 40

// bucketized CSR build
#define BSH 7                    // bucket = dst >> 7  (128 nodes per bucket)
#define NBKT 391                 // ceil(50000 / 128)
#define CAPA 4032                // per-bucket capacity (avg 2046; 12.6MB total, aliases bufB)
#define CHUNK 4096               // edges per binA block
#define NCH ((NE + CHUNK - 1) / CHUNK)   // 196

static inline int cdiv(int a, int b) { return (a + b - 1) / b; }

// ---------------- CSR build: two-phase bucketized counting sort ----------------
__global__ void initcur_k(int* __restrict__ gCursor) {
    int b = blockIdx.x * 256 + threadIdx.x;
    if (b < NBKT) gCursor[b] = b * CAPA;
}

__global__ __launch_bounds__(256)
void binA_k(const int* __restrict__ src, const int* __restrict__ dst,
            uint2* __restrict__ pairs, int* __restrict__ gCursor) {
    __shared__ int hist[512], incl[512], runSt[512], lcur[512], baseSh[512];
    __shared__ uint2 stage[CHUNK];
    const int t = threadIdx.x;
    const int e0 = blockIdx.x * CHUNK;
    const int n = min(CHUNK, NE - e0);

    hist[t] = 0; hist[t + 256] = 0;
    __syncthreads();
    for (int i = t; i < n; i += 256) {
        int d = dst[e0 + i];
        atomicAdd(&hist[d >> BSH], 1);
    }
    __syncthreads();
    incl[t] = hist[t]; incl[t + 256] = hist[t + 256];
    __syncthreads();
    for (int off = 1; off < 512; off <<= 1) {
        int v0 = (t >= off) ? incl[t - off] : 0;
        int v1 = (t + 256 >= off) ? incl[t + 256 - off] : 0;
        __syncthreads();
        incl[t] += v0; incl[t + 256] += v1;
        __syncthreads();
    }
    runSt[t] = incl[t] - hist[t];   runSt[t + 256] = incl[t + 256] - hist[t + 256];
    lcur[t]  = runSt[t];            lcur[t + 256]  = runSt[t + 256];
    __syncthreads();
    for (int i = t; i < n; i += 256) {
        int s = src[e0 + i], d = dst[e0 + i];
        int b = d >> BSH;
        int p = atomicAdd(&lcur[b], 1);
        stage[p] = make_uint2((unsigned)s, (unsigned)d);
    }
    for (int b = t; b < NBKT; b += 256) {
        int c = hist[b];
        baseSh[b] = c ? atomicAdd(&gCursor[b], c) : 0;
    }
    __syncthreads();
    for (int i = t; i < n; i += 256) {
        uint2 p = stage[i];
        int b = (int)(p.y >> BSH);
        int gp = baseSh[b] + (i - runSt[b]);
        if (gp < (b + 1) * CAPA) pairs[gp] = p;
    }
}

__global__ __launch_bounds__(512)
void segscan_k(const int* __restrict__ gCursor, int* __restrict__ segBase) {
    __shared__ int sh[512], orig[512];
    int t = threadIdx.x;
    int c = 0;
    if (t < NBKT) {
        c = gCursor[t] - t * CAPA;
        c = max(0, min(c, CAPA));
    }
    sh[t] = c; orig[t] = c;
    __syncthreads();
    for (int off = 1; off < 512; off <<= 1) {
        int v = (t >= off) ? sh[t - off] : 0;
        __syncthreads();
        sh[t] += v;
        __syncthreads();
    }
    if (t < NBKT) segBase[t] = sh[t] - orig[t];
}

__global__ __launch_bounds__(256)
void binB_k(const uint2* __restrict__ pairs, const int* __restrict__ gCursor,
            const int* __restrict__ segBase, int* __restrict__ cursor,
            float* __restrict__ dinv, int* __restrict__ csr) {
    const int b = blockIdx.x;
    const int nodeBase = b << BSH;
    const int nNodes = min(128, NN - nodeBase);
    int count = gCursor[b] - b * CAPA;
    count = max(0, min(count, CAPA));
    const int seg = segBase[b];
    __shared__ int hist[128], incl[128], lcur[128];
    const int t = threadIdx.x;
    if (t < 128) hist[t] = 0;
    __syncthreads();
    const uint2* bp = pairs + (size_t)b * CAPA;
    for (int i = t; i < count; i += 256) {
        int d = (int)bp[i].y - nodeBase;
        atomicAdd(&hist[d], 1);
    }
    __syncthreads();
    if (t < 128) incl[t] = hist[t];
    __syncthreads();
    for (int off = 1; off < 128; off <<= 1) {
        int v = (t < 128 && t >= off) ? incl[t - off] : 0;
        __syncthreads();
        if (t < 128) incl[t] += v;
        __syncthreads();
    }
    if (t < nNodes) {
        cursor[nodeBase + t] = seg + incl[t];
        dinv[nodeBase + t]   = rsqrtf((float)hist[t] + 1.0f);
        lcur[t] = seg + incl[t] - hist[t];
    }
    __syncthreads();
    for (int i = t; i < count; i += 256) {
        uint2 p = bp[i];
        int d = (int)p.y - nodeBase;
        int pos = atomicAdd(&lcur[d], 1);
        csr[pos] = (int)p.x;
    }
}

// ---------------- register-tiled GEMM (layer-1 front GEMM only) ----------------
template<int K, int F, int CT, int RPT, int BLOCK, bool BIAS, bool SCALE>
__global__ __launch_bounds__(BLOCK)
void gemm_tile_k(const float* __restrict__ X, const float* __restrict__ W,
                 const float* __restrict__ b, const float* __restrict__ dinv,
                 float* __restrict__ Y) {
    constexpr int RT = BLOCK / CT;
    constexpr int TR = RT * RPT;
    constexpr int KT = 32;
    constexpr int KPAD = KT + 1;
    __shared__ float Xs[TR][KPAD];
    __shared__ float Wsh[KT][F];
    const int rowBase = blockIdx.x * TR;
    const int tc = threadIdx.x % CT;
    const int tr = threadIdx.x / CT;

    float acc[RPT][4];
    #pragma unroll
    for (int i = 0; i < RPT; ++i)
        #pragma unroll
        for (int j = 0; j < 4; ++j) acc[i][j] = 0.0f;

    for (int k0 = 0; k0 < K; k0 += KT) {
        constexpr int XL4 = TR * KT / 4;
        for (int l = threadIdx.x; l < XL4; l += BLOCK) {
            int r  = l / (KT / 4);
            int kk = (l % (KT / 4)) * 4;
            float4 v = make_float4(0.f, 0.f, 0.f, 0.f);
            int gr = rowBase + r;
            if (gr < NN) v = *reinterpret_cast<const float4*>(X + (size_t)gr * K + k0 + kk);
            Xs[r][kk + 0] = v.x; Xs[r][kk + 1] = v.y;
            Xs[r][kk + 2] = v.z; Xs[r][kk + 3] = v.w;
        }
        constexpr int WL4 = KT * F / 4;
        for (int l = threadIdx.x; l < WL4; l += BLOCK) {
            int kk = l / (F / 4);
            int c  = (l % (F / 4)) * 4;
            *reinterpret_cast<float4*>(&Wsh[kk][c]) =
                *reinterpret_cast<const float4*>(W + (size_t)(k0 + kk) * F + c);
        }
        __syncthreads();
        #pragma unroll
        for (int kk = 0; kk < KT; ++kk) {
            float wv[4];
            *reinterpret_cast<float4*>(wv) = *reinterpret_cast<const float4*>(&Wsh[kk][tc * 4]);
            #pragma unroll
            for (int i = 0; i < RPT; ++i) {
                float a = Xs[tr * RPT + i][kk];
                acc[i][0] = fmaf(a, wv[0], acc[i][0]);
                acc[i][1] = fmaf(a, wv[1], acc[i][1]);
                acc[i][2] = fmaf(a, wv[2], acc[i][2]);
                acc[i][3] = fmaf(a, wv[3], acc[i][3]);
            }
        }
        __syncthreads();
    }
    #pragma unroll
    for (int i = 0; i < RPT; ++i) {
        int gr = rowBase + tr * RPT + i;
        if (gr < NN) {
            float sc = SCALE ? dinv[gr] : 1.0f;
            float4 v;
            v.x = acc[i][0]; v.y = acc[i][1]; v.z = acc[i][2]; v.w = acc[i][3];
            if (BIAS) {
                v.x += b[tc * 4 + 0]; v.y += b[tc * 4 + 1];
                v.z += b[tc * 4 + 2]; v.w += b[tc * 4 + 3];
            }
            v.x *= sc; v.y *= sc; v.z *= sc; v.w *= sc;
            *reinterpret_cast<float4*>(Y + (size_t)gr * F + tc * 4) = v;
        }
    }
}

// ---------------- hop-1 pull: out[d] = dinv^2 * (in[d] + sum_{s} in[s]), 4-deep ILP ----
template<int F>
__global__ __launch_bounds__(256)
void pull4_k(const float* __restrict__ in, const int* __restrict__ csr,
             const int* __restrict__ cursor, const float* __restrict__ dinv,
             float* __restrict__ out) {
    constexpr int LPN = F / 4;
    constexpr int NPB = 256 / LPN;
    const int t = threadIdx.x;
    const int node = blockIdx.x * NPB + t / LPN;
    const int col  = (t % LPN) * 4;
    if (node >= NN) return;
    const int beg = (node == 0) ? 0 : cursor[node - 1];
    const int end = cursor[node];
    float4 a0 = *reinterpret_cast<const float4*>(in + (size_t)node * F + col);  // self
    float4 a1 = make_float4(0.f, 0.f, 0.f, 0.f);
    float4 a2 = make_float4(0.f, 0.f, 0.f, 0.f);
    float4 a3 = make_float4(0.f, 0.f, 0.f, 0.f);
    int k = beg;
    for (; k + 3 < end; k += 4) {
        int s0 = csr[k], s1 = csr[k + 1], s2 = csr[k + 2], s3 = csr[k + 3];
        float4 v0 = *reinterpret_cast<const float4*>(in + (size_t)s0 * F + col);
        float4 v1 = *reinterpret_cast<const float4*>(in + (size_t)s1 * F + col);
        float4 v2 = *reinterpret_cast<const float4*>(in + (size_t)s2 * F + col);
        float4 v3 = *reinterpret_cast<const float4*>(in + (size_t)s3 * F + col);
        a0.x += v0.x; a0.y += v0.y; a0.z += v0.z; a0.w += v0.w;
        a1.x += v1.x; a1.y += v1.y; a1.z += v1.z; a1.w += v1.w;
        a2.x += v2.x; a2.y += v2.y; a2.z += v2.z; a2.w += v2.w;
        a3.x += v3.x; a3.y += v3.y; a3.z += v3.z; a3.w += v3.w;
    }
    for (; k < end; ++k) {
        int s0 = csr[k];
        float4 v0 = *reinterpret_cast<const float4*>(in + (size_t)s0 * F + col);
        a0.x += v0.x; a0.y += v0.y; a0.z += v0.z; a0.w += v0.w;
    }
    float sc = dinv[node]; sc *= sc;
    float4 r;
    r.x = (a0.x + a1.x + a2.x + a3.x) * sc;
    r.y = (a0.y + a1.y + a2.y + a3.y) * sc;
    r.z = (a0.z + a1.z + a2.z + a3.z) * sc;
    r.w = (a0.w + a1.w + a2.w + a3.w) * sc;
    *reinterpret_cast<float4*>(out + (size_t)node * F + col) = r;
}

// ---------------- fused: hop-2 pull (relu epilogue) + GEMM W2 + dinv scale ----------------
// per node r: h = relu(dinv[r]*(v[r]+sum v[s]) + b1);  out[r] = dinv[r]*(h @ W2)   [64 -> 32]
__global__ __launch_bounds__(256)
void pullgemm2_k(const float* __restrict__ in, const int* __restrict__ csr,
                 const int* __restrict__ cursor, const float* __restrict__ dinv,
                 const float* __restrict__ b1, const float* __restrict__ W2,
                 float* __restrict__ outT) {
    __shared__ float hs[64][68];        // 64 rows, padded stride (16B-aligned, banks spread)
    __shared__ float W2s[64][32];
    const int t = threadIdx.x;
    for (int i = t; i < 64 * 32 / 4; i += 256)
        reinterpret_cast<float4*>(&W2s[0][0])[i] = reinterpret_cast<const float4*>(W2)[i];
    const int nodeBase = blockIdx.x * 64;
    // pull phase: 16 lanes/node, 16 nodes per pass, 4 passes
    #pragma unroll
    for (int pass = 0; pass < 4; ++pass) {
        const int nb = pass * 16 + t / 16;
        const int node = nodeBase + nb;
        const int col = (t % 16) * 4;
        float4 r = make_float4(0.f, 0.f, 0.f, 0.f);
        if (node < NN) {
            const int beg = (node == 0) ? 0 : cursor[node - 1];
            const int end = cursor[node];
            float4 a0 = *reinterpret_cast<const float4*>(in + (size_t)node * 64 + col);
            float4 a1 = make_float4(0.f, 0.f, 0.f, 0.f);
            float4 a2 = make_float4(0.f, 0.f, 0.f, 0.f);
            float4 a3 = make_float4(0.f, 0.f, 0.f, 0.f);
            int k = beg;
            for (; k + 3 < end; k += 4) {
                int s0 = csr[k], s1 = csr[k + 1], s2 = csr[k + 2], s3 = csr[k + 3];
                float4 v0 = *reinterpret_cast<const float4*>(in + (size_t)s0 * 64 + col);
                float4 v1 = *reinterpret_cast<const float4*>(in + (size_t)s1 * 64 + col);
                float4 v2 = *reinterpret_cast<const float4*>(in + (size_t)s2 * 64 + col);
                float4 v3 = *reinterpret_cast<const float4*>(in + (size_t)s3 * 64 + col);
                a0.x += v0.x; a0.y += v0.y; a0.z += v0.z; a0.w += v0.w;
                a1.x += v1.x; a1.y += v1.y; a1.z += v1.z; a1.w += v1.w;
                a2.x += v2.x; a2.y += v2.y; a2.z += v2.z; a2.w += v2.w;
                a3.x += v3.x; a3.y += v3.y; a3.z += v3.z; a3.w += v3.w;
            }
            for (; k < end; ++k) {
                int s0 = csr[k];
                float4 v0 = *reinterpret_cast<const float4*>(in + (size_t)s0 * 64 + col);
                a0.x += v0.x; a0.y += v0.y; a0.z += v0.z; a0.w += v0.w;
            }
            const float sc = dinv[node];
            const float4 bv = *reinterpret_cast<const float4*>(b1 + col);
            r.x = fmaxf((a0.x + a1.x + a2.x + a3.x) * sc + bv.x, 0.f);
            r.y = fmaxf((a0.y + a1.y + a2.y + a3.y) * sc + bv.y, 0.f);
            r.z = fmaxf((a0.z + a1.z + a2.z + a3.z) * sc + bv.z, 0.f);
            r.w = fmaxf((a0.w + a1.w + a2.w + a3.w) * sc + bv.w, 0.f);
        }
        *reinterpret_cast<float4*>(&hs[nb][col]) = r;
    }
    __syncthreads();
    // GEMM phase: 64x64 @ 64x32, thread owns (row r, 8 cols)
    const int r = t / 4;
    const int c0 = (t % 4) * 8;
    float acc[8];
    #pragma unroll
    for (int j = 0; j < 8; ++j) acc[j] = 0.f;
    #pragma unroll 4
    for (int k = 0; k < 64; k += 4) {
        float4 av = *reinterpret_cast<const float4*>(&hs[r][k]);
        #pragma unroll
        for (int kk = 0; kk < 4; ++kk) {
            float a = (&av.x)[kk];
            float4 w0 = *reinterpret_cast<const float4*>(&W2s[k + kk][c0]);
            float4 w1 = *reinterpret_cast<const float4*>(&W2s[k + kk][c0 + 4]);
            acc[0] = fmaf(a, w0.x, acc[0]); acc[1] = fmaf(a, w0.y, acc[1]);
            acc[2] = fmaf(a, w0.z, acc[2]); acc[3] = fmaf(a, w0.w, acc[3]);
            acc[4] = fmaf(a, w1.x, acc[4]); acc[5] = fmaf(a, w1.y, acc[5]);
            acc[6] = fmaf(a, w1.z, acc[6]); acc[7] = fmaf(a, w1.w, acc[7]);
        }
    }
    const int node = nodeBase + r;
    if (node < NN) {
        const float sc = dinv[node];
        float4 o0, o1;
        o0.x = acc[0] * sc; o0.y = acc[1] * sc; o0.z = acc[2] * sc; o0.w = acc[3] * sc;
        o1.x = acc[4] * sc; o1.y = acc[5] * sc; o1.z = acc[6] * sc; o1.w = acc[7] * sc;
        *reinterpret_cast<float4*>(outT + (size_t)node * 32 + c0)     = o0;
        *reinterpret_cast<float4*>(outT + (size_t)node * 32 + c0 + 4) = o1;
    }
}

// ---------------- fused: hop-2 pull (relu epilogue) + final GEMM Wf ----------------
// per node r: emb = relu(dinv[r]*(u[r]+sum u[s]) + b2)  [32] -> embOut
//             logits[r] = emb @ Wf + bf                 [40] -> logits
__global__ __launch_bounds__(256)
void pullgemmF_k(const float* __restrict__ in, const int* __restrict__ csr,
                 const int* __restrict__ cursor, const float* __restrict__ dinv,
                 const float* __restrict__ b2, const float* __restrict__ Wf,
                 const float* __restrict__ bf, float* __restrict__ embOut,
                 float* __restrict__ logits) {
    __shared__ float es[64][36];
    __shared__ float Wfs[32][40];
    __shared__ float bfs[40];
    const int t = threadIdx.x;
    for (int i = t; i < 32 * 40 / 4; i += 256)
        reinterpret_cast<float4*>(&Wfs[0][0])[i] = reinterpret_cast<const float4*>(Wf)[i];
    if (t < 40) bfs[t] = bf[t];
    const int nodeBase = blockIdx.x * 64;
    // pull phase: 8 lanes/node, 32 nodes per pass, 2 passes
    #pragma unroll
    for (int pass = 0; pass < 2; ++pass) {
        const int nb = pass * 32 + t / 8;
        const int node = nodeBase + nb;
        const int col = (t % 8) * 4;
        float4 r = make_float4(0.f, 0.f, 0.f, 0.f);
        if (node < NN) {
            const int beg = (node == 0) ? 0 : cursor[node - 1];
            const int end = cursor[node];
            float4 a0 = *reinterpret_cast<const float4*>(in + (size_t)node * 32 + col);
            float4 a1 = make_float4(0.f, 0.f, 0.f, 0.f);
            float4 a2 = make_float4(0.f, 0.f, 0.f, 0.f);
            float4 a3 = make_float4(0.f, 0.f, 0.f, 0.f);
            int k = beg;
            for (; k + 3 < end; k += 4) {
                int s0 = csr[k], s1 = csr[k + 1], s2 = csr[k + 2], s3 = csr[k + 3];
                float4 v0 = *reinterpret_cast<const float4*>(in + (size_t)s0 * 32 + col);
                float4 v1 = *reinterpret_cast<const float4*>(in + (size_t)s1 * 32 + col);
                float4 v2 = *reinterpret_cast<const float4*>(in + (size_t)s2 * 32 + col);
                float4 v3 = *reinterpret_cast<const float4*>(in + (size_t)s3 * 32 + col);
                a0.x += v0.x; a0.y += v0.y; a0.z += v0.z; a0.w += v0.w;
                a1.x += v1.x; a1.y += v1.y; a1.z += v1.z; a1.w += v1.w;
                a2.x += v2.x; a2.y += v2.y; a2.z += v2.z; a2.w += v2.w;
                a3.x += v3.x; a3.y += v3.y; a3.z += v3.z; a3.w += v3.w;
            }
            for (; k < end; ++k) {
                int s0 = csr[k];
                float4 v0 = *reinterpret_cast<const float4*>(in + (size_t)s0 * 32 + col);
                a0.x += v0.x; a0.y += v0.y; a0.z += v0.z; a0.w += v0.w;
            }
            const float sc = dinv[node];
            const float4 bv = *reinterpret_cast<const float4*>(b2 + col);
            r.x = fmaxf((a0.x + a1.x + a2.x + a3.x) * sc + bv.x, 0.f);
            r.y = fmaxf((a0.y + a1.y + a2.y + a3.y) * sc + bv.y, 0.f);
            r.z = fmaxf((a0.z + a1.z + a2.z + a3.z) * sc + bv.z, 0.f);
            r.w = fmaxf((a0.w + a1.w + a2.w + a3.w) * sc + bv.w, 0.f);
            *reinterpret_cast<float4*>(embOut + (size_t)node * 32 + col) = r;
        }
        *reinterpret_cast<float4*>(&es[nb][col]) = r;
    }
    __syncthreads();
    // GEMM phase: 64x32 @ 32x40, thread owns (row r, 10 cols)
    const int r = t / 4;
    const int c0 = (t % 4) * 10;
    float acc[10];
    #pragma unroll
    for (int j = 0; j < 10; ++j) acc[j] = bfs[c0 + j];
    #pragma unroll 4
    for (int k = 0; k < 32; k += 4) {
        float4 av = *reinterpret_cast<const float4*>(&es[r][k]);
        #pragma unroll
        for (int kk = 0; kk < 4; ++kk) {
            float a = (&av.x)[kk];
            #pragma unroll
            for (int j = 0; j < 10; ++j)
                acc[j] = fmaf(a, Wfs[k + kk][c0 + j], acc[j]);
        }
    }
    const int node = nodeBase + r;
    if (node < NN) {
        float* lp = logits + (size_t)node * 40 + c0;
        #pragma unroll
        for (int j = 0; j < 10; j += 2) {
            float2 o; o.x = acc[j]; o.y = acc[j + 1];
            *reinterpret_cast<float2*>(lp + j) = o;
        }
    }
}

extern "C" void kernel_launch(void* const* d_in, const int* in_sizes, int n_in,
                              void* d_out, int out_size, void* d_ws, size_t ws_size,
                              hipStream_t stream) {
    const float* x  = (const float*)d_in[0];
    const int*   ei = (const int*)d_in[1];
    const float* W1 = (const float*)d_in[2];
    const float* b1 = (const float*)d_in[3];
    const float* W2 = (const float*)d_in[4];
    const float* b2 = (const float*)d_in[5];
    const float* Wf = (const float*)d_in[6];
    const float* bf = (const float*)d_in[7];

    float* out    = (float*)d_out;
    float* embOut = out;                       // [N, 32]
    float* logits = out + (size_t)NN * H2_F;   // [N, 40]

    const int* src = ei;        // edge_index[0]
    const int* dst = ei + NE;   // edge_index[1]

    // workspace layout (all offsets 16B-aligned)
    float* ws       = (float*)d_ws;
    float* dinv     = ws;                           // NN f32
    int*   cursor   = (int*)(ws + NN);              // NN i32
    int*   csr      = cursor + NN;                  // NE i32
    int*   gCursor  = csr + NE;                     // 512 i32
    int*   segBase  = gCursor + 512;                // 512 i32
    float* bufA     = (float*)(segBase + 512);      // NN*64 f32
    float* bufB     = bufA + (size_t)NN * 64;       // NN*64 f32
    uint2* pairs    = (uint2*)bufB;                 // 12.6MB, dead before pull #1

    // ---- CSR build + dinv (bucketized, XCD-local writes) ----
    initcur_k<<<cdiv(NBKT, 256), 256, 0, stream>>>(gCursor);
    binA_k<<<NCH, 256, 0, stream>>>(src, dst, pairs, gCursor);
    segscan_k<<<1, 512, 0, stream>>>(gCursor, segBase);
    binB_k<<<NBKT, 256, 0, stream>>>(pairs, gCursor, segBase, cursor, dinv, csr);

    // ---- layer 1 ----
    gemm_tile_k<IN_F, H1_F, 16, 4, 256, false, true>
        <<<cdiv(NN, 64), 256, 0, stream>>>(x, W1, nullptr, dinv, bufA);          // t = dinv*(xW1)
    pull4_k<H1_F>
        <<<cdiv(NN, 256 / (H1_F / 4)), 256, 0, stream>>>(bufA, csr, cursor, dinv, bufB);  // v = dinv^2*(St)
    pullgemm2_k
        <<<cdiv(NN, 64), 256, 0, stream>>>(bufB, csr, cursor, dinv, b1, W2, bufA);        // t2 = dinv*(relu(dinv*(Sv)+b1)@W2)

    // ---- layer 2 ----
    pull4_k<H2_F>
        <<<cdiv(NN, 256 / (H2_F / 4)), 256, 0, stream>>>(bufA, csr, cursor, dinv, bufB);  // u = dinv^2*(St2)
    pullgemmF_k
        <<<cdiv(NN, 64), 256, 0, stream>>>(bufB, csr, cursor, dinv, b2, Wf, bf, embOut, logits);
}